// Round 6
// baseline (182.716 us; speedup 1.0000x reference)
//
#include <hip/hip_runtime.h>

#define T_LEN 32768
#define ADIM  512
#define NDEC  1024
#define KTAPS 31

// workspace float offsets (no aliasing — ws is huge)
#define WS_BASE 0        // 512   : dec_proj[a] + conv-bias proj        (k0->k1)
#define WS_G    512      // 8192 floats = 32KB: G as bf16 MFMA B-fragments (k0->k1)
#define WS_SARR 16384    // 32768 : sv[t] = 2*(e[t]+mask[t])            (k1->k3)
#define WS_BMAX 49152    // 2048  : per-k1-WAVE online max   (2048 waves)
#define WS_BSUM 51200    // 2048  : per-k1-WAVE online sumexp
#define WS_SSUM 53248    // 1     : S = sum of clipped u                (k3->k4)
#define WS_U    53504    // 32768 : unnormalized u[t]                   (k3->k4)
#define WS_CREP 86272    // 16384 : 32 replicated c~ accumulators (zeroed by k1 blocks 0..63)

typedef __attribute__((ext_vector_type(8))) short bf16x8;
typedef __attribute__((ext_vector_type(4))) float f32x4;

__device__ __forceinline__ float fast_tanh(float x) {
    // tanh(x) = 1 - 2/(exp(2x)+1); ~1e-7 abs err vs 3.5e-4 threshold
    float e = __expf(2.0f * x);
    return 1.0f - 2.0f * __builtin_amdgcn_rcpf(e + 1.0f);
}

__device__ __forceinline__ unsigned short f2bf(float f) {
    // f32 -> bf16 round-to-nearest-even
    unsigned u = __float_as_uint(f);
    return (unsigned short)((u + 0x7FFFu + ((u >> 16) & 1u)) >> 16);
}

// counted waits (T4 idiom): literal-immediate asm + sched fence (rule #18)
#define WAITV8()  do { asm volatile("s_waitcnt vmcnt(8)" ::: "memory"); \
                       __builtin_amdgcn_sched_barrier(0); } while (0)
#define WAITV0()  do { asm volatile("s_waitcnt vmcnt(0)" ::: "memory"); \
                       __builtin_amdgcn_sched_barrier(0); } while (0)
#define WAITL0()  do { asm volatile("s_waitcnt lgkmcnt(0)" ::: "memory"); \
                       __builtin_amdgcn_sched_barrier(0); } while (0)

// ---------------- K0: dec_proj+bias -> base[512]; G B-fragments (bf16); zero SSUM -----
// G-fragment layout for mfma_f32_16x16x32_bf16 B-operand: per a-tile `at` (16 a's),
// lane l holds B[k][col] for col = l&15, k = 8*(l>>4)+i (i=0..7 contiguous bf16).
// Stored at u16 index (at*64 + l)*8 + i. k=31 is the zero pad tap (K=32).
__global__ __launch_bounds__(256) void k0_prep(
        const float* __restrict__ dec_z, const float* __restrict__ conv_w,
        const float* __restrict__ conv_b, const float* __restrict__ W_att,
        const float* __restrict__ W_dec, float* __restrict__ ws) {
    int b = blockIdx.x, tid = threadIdx.x;
    int lane = tid & 63, wave = tid >> 6;
    if (b < 64) {
        if (b == 0 && tid == 0) ws[WS_SSUM] = 0.f;
        // 8 a's per block, wave handles 2 (64-lane dot over 1024)
        for (int s = 0; s < 2; ++s) {
            int a = b * 8 + wave * 2 + s;
            float sum = 0.f;
            #pragma unroll
            for (int i = 0; i < 16; ++i)
                sum += W_dec[a * NDEC + i * 64 + lane] * dec_z[i * 64 + lane];
            #pragma unroll
            for (int off = 32; off > 0; off >>= 1) sum += __shfl_xor(sum, off);
            if (lane == 0) {
                float bias = 0.f;
                #pragma unroll
                for (int c = 0; c < 32; ++c) bias += conv_b[c] * W_att[a * 32 + c];
                ws[WS_BASE + a] = sum + bias;
            }
        }
    } else {
        int k = b - 64;                 // 0..31 (31 = zero pad)
        unsigned short* Gf = (unsigned short*)(ws + WS_G);
        for (int s = 0; s < 2; ++s) {
            int a = 2 * tid + s;
            float g = 0.f;
            if (k < KTAPS) {
                #pragma unroll
                for (int c = 0; c < 32; ++c)
                    g += conv_w[c * KTAPS + k] * W_att[a * 32 + c];
            }
            int at = a >> 4, col = a & 15;
            int l = col | ((k >> 3) << 4), i = k & 7;
            Gf[(at * 64 + l) * 8 + i] = f2bf(g);
        }
    }
}

// ---------------- K1 v4: wave-private double-buffered DMA pipeline (0 barriers) ------
// R5 DIAGNOSIS: k1 stuck at ~1.8 TB/s because __syncthreads drains vmcnt(0) each tile:
// per-CU in-flight bytes collapse below the ~22 KB Little's-law target. FIX (T3/T4):
// counted vmcnt, never 0 in the loop. Each WAVE owns one 16t x 512a tile as four
// 16t x 128a chunks (8 KB) in PRIVATE double-buffered LDS -> no cross-wave sharing,
// no __syncthreads, and s_waitcnt is per-wave so counted waits are race-free.
// Schedule: stage(0),stage(1); [vmcnt(8) -> compute(c) -> lgkmcnt(0) -> stage(c+2)].
// While computing chunk c, chunk c+1's 8 DMAs stay in flight. 512 blocks x 256 thr
// (4 waves), 64 KB LDS -> 2 blocks/CU: all 2048 waves co-resident, one generation.
__global__ __launch_bounds__(256, 2) void k1_energy(
        const float* __restrict__ att_prev, const float* __restrict__ pre,
        const float* __restrict__ mask, const float* __restrict__ W_g,
        const float* __restrict__ b_g, float* __restrict__ ws) {
    __shared__ float lds[4][2][2048];   // [wave][buf][16t x 128a] = 64 KB
    int tid = threadIdx.x, lane = tid & 63, wave = tid >> 6;
    int W = blockIdx.x * 4 + wave;      // global wave id = tile id, 0..2047
    int t0 = W * 16;
    int row = lane & 15, g4 = lane >> 4;

    // zero c~ replicas for k3 (kernel boundary = the fence): 64 blocks x 256 floats
    if (blockIdx.x < 64) ws[WS_CREP + blockIdx.x * 256 + tid] = 0.f;

    // DMA source base for this wave: instr i covers rows {2i, 2i+1} of chunk c:
    // lane -> row = 2i + (lane>>5), col = c*128 + (lane&31)*4. LDS lands linearly at
    // buf + i*256 + lane*4, i.e. buf[t*128 + aoff] for (t, aoff) in the chunk.
    const float* src0 = pre + (size_t)(t0 + (lane >> 5)) * ADIM + (lane & 31) * 4;

#define STAGE(c, buf) do {                                                          \
        const float* _s = src0 + (c) * 128;                                         \
        _Pragma("unroll")                                                           \
        for (int i = 0; i < 8; ++i) {                                               \
            __builtin_amdgcn_global_load_lds(                                       \
                (const __attribute__((address_space(1))) void*)(_s + (size_t)(2*i) * ADIM), \
                (__attribute__((address_space(3))) void*)((buf) + i * 256),         \
                16, 0, 0);                                                          \
        }                                                                           \
    } while (0)

    // A fragment (R2-verified): A[t][k] = ap[t0 + t + k - 15]; lane: t=row, k=8*g4+i
    bf16x8 afrag;
    int abase = t0 - 15 + row + g4 * 8;
    #pragma unroll
    for (int i = 0; i < 8; ++i) {
        int idx = abase + i;
        float v = (idx >= 0 && idx < T_LEN) ? att_prev[idx] : 0.f;
        afrag[i] = (short)f2bf(v);
    }

    float* buf0 = &lds[wave][0][0];
    float* buf1 = &lds[wave][1][0];
    const unsigned short* Gf = (const unsigned short*)(ws + WS_G);
    float e_acc[4] = {0.f, 0.f, 0.f, 0.f};

#define COMPUTE(c, buf) do {                                                        \
        _Pragma("unroll")                                                           \
        for (int p = 0; p < 8; ++p) {                                               \
            int at = (c) * 8 + p;                                                   \
            int ac = at * 16 + row;                                                 \
            bf16x8 bfrag = *(const bf16x8*)(Gf + (size_t)(at * 64 + lane) * 8);     \
            float bs = ws[WS_BASE + ac];                                            \
            f32x4 cc = {bs, bs, bs, bs};                                            \
            cc = __builtin_amdgcn_mfma_f32_16x16x32_bf16(afrag, bfrag, cc, 0, 0, 0);\
            float wgv = W_g[ac];                                                    \
            _Pragma("unroll")                                                       \
            for (int r = 0; r < 4; ++r) {                                           \
                float pv = (buf)[(g4 * 4 + r) * 128 + p * 16 + row];                \
                e_acc[r] = fmaf(fast_tanh(cc[r] + pv), wgv, e_acc[r]);              \
            }                                                                       \
        }                                                                           \
    } while (0)

    STAGE(0, buf0);
    STAGE(1, buf1);

    WAITV8();             // chunk 0 landed; chunk 1 still in flight
    COMPUTE(0, buf0);
    WAITL0();             // buf0 reads in regs before overwrite
    STAGE(2, buf0);

    WAITV8();             // chunk 1 landed; chunk 2 in flight
    COMPUTE(1, buf1);
    WAITL0();
    STAGE(3, buf1);

    WAITV8();             // chunk 2 landed; chunk 3 in flight
    COMPUTE(2, buf0);

    WAITV0();             // final drain (epilogue only)
    COMPUTE(3, buf1);

#undef STAGE
#undef COMPUTE

    // reduce e_acc over the 16 a-columns (row lanes); result uniform per row-group
    #pragma unroll
    for (int r = 0; r < 4; ++r) {
        float s = e_acc[r];
        s += __shfl_xor(s, 1); s += __shfl_xor(s, 2);
        s += __shfl_xor(s, 4); s += __shfl_xor(s, 8);
        e_acc[r] = s;     // e for t = t0 + g4*4 + r
    }

    float bg = b_g[0];
    float m = -1e30f, z = 0.f;
    float sv[4];
    #pragma unroll
    for (int r = 0; r < 4; ++r) {
        int t = t0 + g4 * 4 + r;
        sv[r] = 2.0f * (e_acc[r] + bg + mask[t]);
        float mn = fmaxf(m, sv[r]);
        z = z * __expf(m - mn) + __expf(sv[r] - mn);
        m = mn;
    }
    if (row == 0) {
        #pragma unroll
        for (int r = 0; r < 4; ++r) ws[WS_SARR + t0 + g4 * 4 + r] = sv[r];
    }
    // combine (M,Z) across the 4 g4 groups (lane bits 4,5)
    #pragma unroll
    for (int off = 16; off <= 32; off <<= 1) {
        float mo = __shfl_xor(m, off), zo = __shfl_xor(z, off);
        float mn = fmaxf(m, mo);
        z = z * __expf(m - mn) + zo * __expf(mo - mn);
        m = mn;
    }
    if (lane == 0) { ws[WS_BMAX + W] = m; ws[WS_BSUM + W] = z; }
}

// ---------------- K3 v3: LN-shaped streaming context (unchanged from R5) -------------
// 512 blocks x 512 thr, thread owns 4 a-cols over 64 t's; loads hoisted 8-deep;
// (M,Z) prologue reads the 2048 per-wave pairs (8 indep loads/lane + butterfly).
__global__ __launch_bounds__(512, 4) void k3_context(
        const float* __restrict__ att_prev, const float* __restrict__ enc_h,
        float* __restrict__ ws) {
    __shared__ float wmz[16];
    __shared__ float cbuf[4 * 512];
    int tid = threadIdx.x, lane = tid & 63, wave = tid >> 6;

    float mo[4], zo[4];
    #pragma unroll
    for (int k = 0; k < 4; ++k) {
        mo[k] = ws[WS_BMAX + (wave + 8 * k) * 64 + lane];
        zo[k] = ws[WS_BSUM + (wave + 8 * k) * 64 + lane];
    }
    float m = mo[0], z = zo[0];
    #pragma unroll
    for (int k = 1; k < 4; ++k) {
        float mn = fmaxf(m, mo[k]);
        z = z * __expf(m - mn) + zo[k] * __expf(mo[k] - mn);
        m = mn;
    }
    #pragma unroll
    for (int off = 32; off > 0; off >>= 1) {
        float mx = __shfl_xor(m, off), zx = __shfl_xor(z, off);
        float mn = fmaxf(m, mx);
        z = z * __expf(m - mn) + zx * __expf(mx - mn);
        m = mn;
    }
    if (lane == 0) { wmz[wave] = m; wmz[8 + wave] = z; }
    __syncthreads();
    float M = wmz[0], Z = wmz[8];
    #pragma unroll
    for (int w = 1; w < 8; ++w) {
        float mn = fmaxf(M, wmz[w]);
        Z = Z * __expf(M - mn) + wmz[8 + w] * __expf(wmz[w] - mn);
        M = mn;
    }
    float invZ = 1.0f / Z;

    int team = tid >> 7, l = tid & 127;
    int a4 = 4 * l;
    float4 acc = make_float4(0.f, 0.f, 0.f, 0.f);

    #pragma unroll 1
    for (int half = 0; half < 2; ++half) {
        int t0 = blockIdx.x * 64 + half * 32;
        int tb = t0 + team * 8;

        float u[8];
        #pragma unroll
        for (int i = 0; i < 8; ++i) {
            int t = tb + i;
            float ap0 = att_prev[t];
            float apm = (t > 0) ? att_prev[t - 1] : 0.f;
            u[i] = fmaxf((ap0 + apm) * __expf(ws[WS_SARR + t] - M) * invZ, 1e-6f);
        }
        float4 e[8];
        #pragma unroll
        for (int i = 0; i < 8; ++i)
            e[i] = *(const float4*)(enc_h + (size_t)(tb + i) * ADIM + a4);
        #pragma unroll
        for (int i = 0; i < 8; ++i) {
            acc.x = fmaf(u[i], e[i].x, acc.x);
            acc.y = fmaf(u[i], e[i].y, acc.y);
            acc.z = fmaf(u[i], e[i].z, acc.z);
            acc.w = fmaf(u[i], e[i].w, acc.w);
        }

        if (wave == 0 && lane < 32) {
            int t = t0 + lane;
            float ap0 = att_prev[t];
            float apm = (t > 0) ? att_prev[t - 1] : 0.f;
            float uu = fmaxf((ap0 + apm) * __expf(ws[WS_SARR + t] - M) * invZ, 1e-6f);
            ws[WS_U + t] = uu;
            float s = uu;
            #pragma unroll
            for (int off = 16; off > 0; off >>= 1) s += __shfl_xor(s, off, 32);
            if (lane == 0) atomicAdd(&ws[WS_SSUM], s);
        }
    }

    if (team != 0) *(float4*)&cbuf[team * 512 + a4] = acc;
    __syncthreads();
    if (team == 0) {
        float4 b1 = *(const float4*)&cbuf[1 * 512 + a4];
        float4 b2 = *(const float4*)&cbuf[2 * 512 + a4];
        float4 b3 = *(const float4*)&cbuf[3 * 512 + a4];
        float* rep = ws + WS_CREP + (blockIdx.x & 31) * 512;
        atomicAdd(&rep[a4 + 0], acc.x + b1.x + b2.x + b3.x);
        atomicAdd(&rep[a4 + 1], acc.y + b1.y + b2.y + b3.y);
        atomicAdd(&rep[a4 + 2], acc.z + b1.z + b2.z + b3.z);
        atomicAdd(&rep[a4 + 3], acc.w + b1.w + b2.w + b3.w);
    }
}

// ---------------- K4: c = (sum replicas)/S -> out[0:512]; w = u/S -> out[512:] --------
__global__ __launch_bounds__(512) void k4_final(
        const float* __restrict__ ws, float* __restrict__ out) {
    int b = blockIdx.x, tid = threadIdx.x;
    float invS = 1.0f / ws[WS_SSUM];
    if (b == 0) {
        float acc = 0.f;
        #pragma unroll
        for (int r = 0; r < 32; ++r) acc += ws[WS_CREP + r * 512 + tid];
        out[tid] = acc * invS;
    } else {
        int i = (b - 1) * 512 + tid;
        out[512 + i] = ws[WS_U + i] * invS;
    }
}

extern "C" void kernel_launch(void* const* d_in, const int* in_sizes, int n_in,
                              void* d_out, int out_size, void* d_ws, size_t ws_size,
                              hipStream_t stream) {
    const float* dec_z    = (const float*)d_in[0];
    const float* att_prev = (const float*)d_in[1];
    const float* pre      = (const float*)d_in[2];
    const float* enc_h    = (const float*)d_in[3];
    const float* mask     = (const float*)d_in[4];
    const float* conv_w   = (const float*)d_in[5];
    const float* conv_b   = (const float*)d_in[6];
    const float* W_att    = (const float*)d_in[7];
    const float* W_dec    = (const float*)d_in[8];
    const float* W_g      = (const float*)d_in[9];
    const float* b_g      = (const float*)d_in[10];
    float* out = (float*)d_out;
    float* ws  = (float*)d_ws;

    k0_prep   <<<96,  256, 0, stream>>>(dec_z, conv_w, conv_b, W_att, W_dec, ws);
    k1_energy <<<512, 256, 0, stream>>>(att_prev, pre, mask, W_g, b_g, ws);
    k3_context<<<512, 512, 0, stream>>>(att_prev, enc_h, ws);
    k4_final  <<<65,  512, 0, stream>>>(ws, out);
}